// Round 8
// baseline (227.607 us; speedup 1.0000x reference)
//
#include <hip/hip_runtime.h>
#include <hip/hip_fp16.h>

typedef _Float16 f16x8 __attribute__((ext_vector_type(8)));
typedef _Float16 f16x4 __attribute__((ext_vector_type(4)));
typedef float    f32x4 __attribute__((ext_vector_type(4)));

#define T_STEPS 32
#define NROWS   10000
#define DDIM    256
#define ROWS_PB 40                     // 250 blocks exactly (10000/40), no tail
#define TILE_ROWS 48                   // LDS tile kept at 48 rows (8 pad rows)
#define TILE_B  (TILE_ROWS * 512)      // 24576 B per f16 tile
#define NCHUNK4 (ROWS_PB * DDIM / 4)   // 2560 f32x4 chunks per H slab
#define NCHUNK16 (ROWS_PB * 32)        // 1280 16B chunks per S tile (real rows)

// ---------------------------------------------------------------------------
// Pre-kernel: f32 weights -> f16 MFMA B-fragments.
// Fragment (ct,ks), ct=0..15, ks=0..7:
//   dst[((ct*8+ks)*64+lane)*8 + j] = W[ct*16 + (lane&15)][ks*32 + (lane>>4)*8 + j]
// ---------------------------------------------------------------------------
__global__ __launch_bounds__(256) void cvt_weights_kernel(
    const float* __restrict__ Aw, const float* __restrict__ Bw,
    _Float16* __restrict__ wsA, _Float16* __restrict__ wsB)
{
    int tid  = blockIdx.x * 256 + threadIdx.x;      // 0..8191
    int lane = tid & 63;
    int ks   = (tid >> 6) & 7;
    int ct   = tid >> 9;                            // 0..15
    int e     = ct * 16 + (lane & 15);
    int dbase = ks * 32 + (lane >> 4) * 8;
    size_t src = (size_t)e * DDIM + dbase;
    size_t dst = (size_t)tid * 8;
#pragma unroll
    for (int j = 0; j < 8; ++j) {
        wsA[dst + j] = (_Float16)Aw[src + j];
        wsB[dst + j] = (_Float16)Bw[src + j];
    }
}

// Barrier WITHOUT the compiler's vmcnt(0) drain: LDS deps are covered by
// lgkmcnt(0); global stores / prefetch loads keep draining across steps.
__device__ __forceinline__ void barrier_lgkm() {
    asm volatile("s_waitcnt lgkmcnt(0)\n\ts_barrier" ::: "memory");
}

// ---------------------------------------------------------------------------
// Fused SSM (R7 schedule + per-wave K-rotation). Block = 40 rows x 32 steps.
// 16 waves; wave w owns cols [16w,16w+16). Weights in registers, loaded
// PRE-ROTATED by kb = wave&7 so the K-loop's register indices stay
// compile-time while wave w reads LDS K-slot (ks+kb)&7 at iteration ks —
// de-phasing the 16 waves' bank sequences (inter-wave conflict fix).
// Double-buffered LDS H tile + S exchange; ONE lgkm-only barrier per step;
// out[t] stored from LDS readback with full 128B-line f32x4 stores.
// ---------------------------------------------------------------------------
__global__ __launch_bounds__(1024, 4) void ssm_fused_kernel(
    const float* __restrict__ H,          // [T][N][D] f32
    const _Float16* __restrict__ WaF,     // frag-permuted f16
    const _Float16* __restrict__ WbF,
    const float* __restrict__ bias,       // [D] f32
    float* __restrict__ out)              // [T][N][D] f32
{
    // Hbuf0 | Hbuf1 | Sbuf0 | Sbuf1, each 24 KiB (96 KiB total)
    __shared__ char lds[4 * TILE_B];

    const int tid  = threadIdx.x;
    const int lane = tid & 63;
    const int wave = tid >> 6;            // 0..15 == ct (16-col tile)
    const int lr   = lane & 15;
    const int kg   = lane >> 4;           // 0..3
    const int kb   = wave & 7;            // K-rotation offset for this wave
    const int row0 = blockIdx.x * ROWS_PB;
    const bool third = (tid < NCHUNK4 - 2048);   // tid < 512: owns a 3rd chunk

    // ---- one-time: weight fragments -> registers, PRE-ROTATED by kb.
    //      wA[j]/wB[j] hold physical K-slot (j+kb)&7.
    f16x8 wA[8], wB[8];
#pragma unroll
    for (int j = 0; j < 8; ++j) {
        int ksrc = (j + kb) & 7;                       // runtime addr, static reg idx
        size_t o = (size_t)((wave * 8 + ksrc) * 64 + lane) * 8;
        wA[j] = *reinterpret_cast<const f16x8*>(WaF + o);
        wB[j] = *reinterpret_cast<const f16x8*>(WbF + o);
    }

    const float bv = bias[wave * 16 + lr];

    // Block's H slab at step t is contiguous: H + t*N*D + row0*D, 40960 floats.
    const float* Hslab = H + (size_t)row0 * DDIM;

    // ---- prologue: stage H_0 (f32 -> f16, swizzled) into Hbuf0 ----
    // flat chunks: idx in [0,2560); r = idx>>6, f16-byte = (idx&63)*8
    f32x4 hreg[3];
#pragma unroll
    for (int j = 0; j < 3; ++j) {
        int idx = j * 1024 + tid;
        if (j < 2 || third)
            hreg[j] = *reinterpret_cast<const f32x4*>(Hslab + (size_t)idx * 4);
    }
#pragma unroll
    for (int j = 0; j < 3; ++j) {
        int idx = j * 1024 + tid;
        if (j < 2 || third) {
            int r = idx >> 6;
            f16x4 v;
#pragma unroll
            for (int k = 0; k < 4; ++k) v[k] = (_Float16)hreg[j][k];
            *reinterpret_cast<f16x4*>(lds + r * 512 + (((idx & 63) * 8) ^ ((r & 7) << 4))) = v;
        }
    }
    __syncthreads();

    f32x4 acc[3];

    for (int t = 0; t < T_STEPS; ++t) {
        const int cur = t & 1;
        char* Hc = lds + cur * TILE_B;
        char* Hn = lds + (cur ^ 1) * TILE_B;
        char* Sc = lds + 2 * TILE_B + cur * TILE_B;
        char* Sn = lds + 2 * TILE_B + (cur ^ 1) * TILE_B;
        const bool has_next = (t + 1 < T_STEPS);

        // 1. issue next-step H loads (hidden under this step's K-loop)
        if (has_next) {
            const float* Ht1 = Hslab + (size_t)(t + 1) * NROWS * DDIM;
#pragma unroll
            for (int j = 0; j < 3; ++j) {
                int idx = j * 1024 + tid;
                if (j < 2 || third)
                    hreg[j] = *reinterpret_cast<const f32x4*>(Ht1 + (size_t)idx * 4);
            }
        }

        // 2. init acc with bias (C/D: col = lane&15)
#pragma unroll
        for (int nt = 0; nt < 3; ++nt)
#pragma unroll
            for (int i = 0; i < 4; ++i) acc[nt][i] = bv;

        // 3. K-loop, staggered: iteration ks touches physical K-slot
        //    (ks+kb)&7; wB/wA are pre-rotated to match. LDS+MFMA only.
        __builtin_amdgcn_s_setprio(1);
#pragma unroll
        for (int ks = 0; ks < 8; ++ks) {
            int kphys = ks + kb; kphys &= 7;           // per-wave uniform
            const int cbyte = kphys * 64 + kg * 16;
            f16x8 hfrag[3];
#pragma unroll
            for (int nt = 0; nt < 3; ++nt) {
                int r = nt * 16 + lr;
                hfrag[nt] = *reinterpret_cast<const f16x8*>(
                    Hc + r * 512 + (cbyte ^ ((r & 7) << 4)));
            }
#pragma unroll
            for (int nt = 0; nt < 3; ++nt)
                acc[nt] = __builtin_amdgcn_mfma_f32_16x16x32_f16(hfrag[nt], wB[ks], acc[nt], 0, 0, 0);
            if (t > 0) {
                f16x8 sfrag[3];
#pragma unroll
                for (int nt = 0; nt < 3; ++nt) {
                    int r = nt * 16 + lr;
                    sfrag[nt] = *reinterpret_cast<const f16x8*>(
                        Sc + r * 512 + (cbyte ^ ((r & 7) << 4)));
                }
#pragma unroll
                for (int nt = 0; nt < 3; ++nt)
                    acc[nt] = __builtin_amdgcn_mfma_f32_16x16x32_f16(sfrag[nt], wA[ks], acc[nt], 0, 0, 0);
            }
        }
        __builtin_amdgcn_s_setprio(0);

        // 4a. stage H_{t+1} (f16) into Hn (vmcnt waits happen here by dep)
        if (has_next) {
#pragma unroll
            for (int j = 0; j < 3; ++j) {
                int idx = j * 1024 + tid;
                if (j < 2 || third) {
                    int r = idx >> 6;
                    f16x4 v;
#pragma unroll
                    for (int k = 0; k < 4; ++k) v[k] = (_Float16)hreg[j][k];
                    *reinterpret_cast<f16x4*>(Hn + r * 512 + (((idx & 63) * 8) ^ ((r & 7) << 4))) = v;
                }
            }
        }

        // 4b. S_t -> Sn (f16, swizzled). Rows 40-47 are pad (never stored).
#pragma unroll
        for (int nt = 0; nt < 3; ++nt) {
            const int c = wave * 16 + lr;
#pragma unroll
            for (int i = 0; i < 4; ++i) {
                int r = nt * 16 + kg * 4 + i;
                *reinterpret_cast<_Float16*>(Sn + r * 512 + ((c * 2) ^ ((r & 7) << 4))) =
                    (_Float16)acc[nt][i];
            }
        }

        // 5. single lgkm-only barrier: Sn/Hn complete & visible; global
        //    stores keep draining in the background.
        barrier_lgkm();

        // 6. epilogue: row-contiguous readback of Sn -> coalesced f32 stores.
        //    1280 chunks of 16B (40 real rows x 32 chunks/row).
        float* Ot = out + (size_t)t * NROWS * DDIM;
#pragma unroll
        for (int p = 0; p < 2; ++p) {
            int idx = p * 1024 + tid;
            if (idx < NCHUNK16) {
                int r   = idx >> 5;                // 0..39 (real rows only)
                int c16 = idx & 31;                // 16B chunk within row
                f16x8 v = *reinterpret_cast<const f16x8*>(
                    Sn + r * 512 + ((c16 * 16) ^ ((r & 7) << 4)));
                int gr = row0 + r;
                f32x4 lo, hi;
#pragma unroll
                for (int k = 0; k < 4; ++k) { lo[k] = (float)v[k]; hi[k] = (float)v[k + 4]; }
                float* dst = Ot + (size_t)gr * DDIM + c16 * 8;
                *reinterpret_cast<f32x4*>(dst)     = lo;
                *reinterpret_cast<f32x4*>(dst + 4) = hi;
            }
        }
        // no second barrier: next step's LDS writes target the opposite
        // buffers; this epilogue's reads complete before this wave's next
        // lgkmcnt(0)+barrier, which precedes any conflicting write (t+2).
    }
}

extern "C" void kernel_launch(void* const* d_in, const int* in_sizes, int n_in,
                              void* d_out, int out_size, void* d_ws, size_t ws_size,
                              hipStream_t stream)
{
    const float* H  = (const float*)d_in[0];
    const float* Aw = (const float*)d_in[1];
    const float* Bw = (const float*)d_in[2];
    const float* Bb = (const float*)d_in[3];
    float* out      = (float*)d_out;

    _Float16* wsA = (_Float16*)d_ws;         // 128 KiB
    _Float16* wsB = wsA + 65536;             // 128 KiB

    cvt_weights_kernel<<<32, 256, 0, stream>>>(Aw, Bw, wsA, wsB);

    int nblocks = NROWS / ROWS_PB;           // 250 (10000/40, exact)
    ssm_fused_kernel<<<nblocks, 1024, 0, stream>>>(H, wsA, wsB, Bb, out);
}

// Round 9
// 139.839 us; speedup vs baseline: 1.6276x; 1.6276x over previous
//
#include <hip/hip_runtime.h>
#include <hip/hip_fp16.h>

typedef _Float16 f16x8 __attribute__((ext_vector_type(8)));
typedef _Float16 f16x4 __attribute__((ext_vector_type(4)));
typedef float    f32x4 __attribute__((ext_vector_type(4)));

#define T_STEPS 32
#define NROWS   10000
#define DDIM    256
#define ROWS_PB 40                     // 250 blocks exactly (10000/40), no tail
#define TILE_ROWS 48                   // LDS tile rows (40 real + 8 pad)
#define TILE_B  (TILE_ROWS * 512)      // 24576 B per f16 tile
#define NCHUNK4 (ROWS_PB * DDIM / 4)   // 2560 f32x4 chunks per H slab
#define NCHUNK16 (ROWS_PB * 32)        // 1280 16B chunks per S tile (real rows)

// ---------------------------------------------------------------------------
// Pre-kernel: f32 weights -> f16 MFMA B-fragments.
// Fragment (ct,ks), ct=0..15, ks=0..7:
//   dst[((ct*8+ks)*64+lane)*8 + j] = W[ct*16 + (lane&15)][ks*32 + (lane>>4)*8 + j]
// ---------------------------------------------------------------------------
__global__ __launch_bounds__(256) void cvt_weights_kernel(
    const float* __restrict__ Aw, const float* __restrict__ Bw,
    _Float16* __restrict__ wsA, _Float16* __restrict__ wsB)
{
    int tid  = blockIdx.x * 256 + threadIdx.x;      // 0..8191
    int lane = tid & 63;
    int ks   = (tid >> 6) & 7;
    int ct   = tid >> 9;                            // 0..15
    int e     = ct * 16 + (lane & 15);
    int dbase = ks * 32 + (lane >> 4) * 8;
    size_t src = (size_t)e * DDIM + dbase;
    size_t dst = (size_t)tid * 8;
#pragma unroll
    for (int j = 0; j < 8; ++j) {
        wsA[dst + j] = (_Float16)Aw[src + j];
        wsB[dst + j] = (_Float16)Bw[src + j];
    }
}

// Barrier WITHOUT the compiler's vmcnt(0) drain: LDS deps are covered by
// lgkmcnt(0); global stores / prefetch loads keep draining across steps.
__device__ __forceinline__ void barrier_lgkm() {
    asm volatile("s_waitcnt lgkmcnt(0)\n\ts_barrier" ::: "memory");
}

// ---------------------------------------------------------------------------
// Fused SSM, A-fragment-reuse layout. Block = 40 rows x 32 steps.
// 8 waves (512 thr); wave w owns cols [32w, 32w+32) = 2 col-tiles (et=0,1).
// Each A-fragment (H/S) read from LDS feeds 2 MFMAs -> total LDS A-traffic
// halves vs the 16-wave layout (384 KB/step vs 768). Weights in registers
// (128 VGPR/lane: 2 ct x 8 ks x {A,B}). Double-buffered LDS H + S tiles,
// ONE lgkm-only barrier per step, full-128B-line f32 stores from LDS
// readback. __launch_bounds__(512,2): ~200 VGPRs live, no spill allowed.
// ---------------------------------------------------------------------------
__global__ __launch_bounds__(512, 2) void ssm_fused_kernel(
    const float* __restrict__ H,          // [T][N][D] f32
    const _Float16* __restrict__ WaF,     // frag-permuted f16
    const _Float16* __restrict__ WbF,
    const float* __restrict__ bias,       // [D] f32
    float* __restrict__ out)              // [T][N][D] f32
{
    // Hbuf0 | Hbuf1 | Sbuf0 | Sbuf1, each 24 KiB (96 KiB total)
    __shared__ char lds[4 * TILE_B];

    const int tid  = threadIdx.x;
    const int lane = tid & 63;
    const int wc   = tid >> 6;            // 0..7: 32-col strip
    const int lr   = lane & 15;
    const int kg   = lane >> 4;           // 0..3
    const int row0 = blockIdx.x * ROWS_PB;

    // ---- one-time: this wave's weight fragments (2 col-tiles) -> 128 VGPRs
    f16x8 wA[2][8], wB[2][8];
#pragma unroll
    for (int et = 0; et < 2; ++et) {
        const int ct = wc * 2 + et;
#pragma unroll
        for (int ks = 0; ks < 8; ++ks) {
            size_t o = (size_t)((ct * 8 + ks) * 64 + lane) * 8;
            wA[et][ks] = *reinterpret_cast<const f16x8*>(WaF + o);
            wB[et][ks] = *reinterpret_cast<const f16x8*>(WbF + o);
        }
    }

    float bv[2];
#pragma unroll
    for (int et = 0; et < 2; ++et) bv[et] = bias[wc * 32 + et * 16 + lr];

    // Block's H slab at step t: H + t*N*D + row0*D, 10240 floats, contiguous.
    const float* Hslab = H + (size_t)row0 * DDIM;

    // ---- prologue: stage H_0 (f32 -> f16, swizzled) into Hbuf0 ----
    // flat chunks: idx in [0,2560); 512 thr x 5 chunks exactly, no masking.
    f32x4 hreg[5];
#pragma unroll
    for (int j = 0; j < 5; ++j) {
        int idx = j * 512 + tid;
        hreg[j] = *reinterpret_cast<const f32x4*>(Hslab + (size_t)idx * 4);
    }
#pragma unroll
    for (int j = 0; j < 5; ++j) {
        int idx = j * 512 + tid;
        int r = idx >> 6;
        f16x4 v;
#pragma unroll
        for (int k = 0; k < 4; ++k) v[k] = (_Float16)hreg[j][k];
        *reinterpret_cast<f16x4*>(lds + r * 512 + (((idx & 63) * 8) ^ ((r & 7) << 4))) = v;
    }
    __syncthreads();

    f32x4 acc[3][2];

    for (int t = 0; t < T_STEPS; ++t) {
        const int cur = t & 1;
        char* Hc = lds + cur * TILE_B;
        char* Hn = lds + (cur ^ 1) * TILE_B;
        char* Sc = lds + 2 * TILE_B + cur * TILE_B;
        char* Sn = lds + 2 * TILE_B + (cur ^ 1) * TILE_B;
        const bool has_next = (t + 1 < T_STEPS);

        // 1. issue next-step H loads (hidden under this step's K-loop)
        if (has_next) {
            const float* Ht1 = Hslab + (size_t)(t + 1) * NROWS * DDIM;
#pragma unroll
            for (int j = 0; j < 5; ++j) {
                int idx = j * 512 + tid;
                hreg[j] = *reinterpret_cast<const f32x4*>(Ht1 + (size_t)idx * 4);
            }
        }

        // 2. init acc with bias (C/D: col = lane&15)
#pragma unroll
        for (int nt = 0; nt < 3; ++nt)
#pragma unroll
            for (int et = 0; et < 2; ++et)
#pragma unroll
                for (int i = 0; i < 4; ++i) acc[nt][et][i] = bv[et];

        // 3. K-loop: each A-fragment read feeds BOTH col-tiles (2 MFMAs).
        __builtin_amdgcn_s_setprio(1);
#pragma unroll
        for (int ks = 0; ks < 8; ++ks) {
            const int cbyte = ks * 64 + kg * 16;
            f16x8 hfrag[3];
#pragma unroll
            for (int nt = 0; nt < 3; ++nt) {
                int r = nt * 16 + lr;
                hfrag[nt] = *reinterpret_cast<const f16x8*>(
                    Hc + r * 512 + (cbyte ^ ((r & 7) << 4)));
            }
#pragma unroll
            for (int nt = 0; nt < 3; ++nt)
#pragma unroll
                for (int et = 0; et < 2; ++et)
                    acc[nt][et] = __builtin_amdgcn_mfma_f32_16x16x32_f16(hfrag[nt], wB[et][ks], acc[nt][et], 0, 0, 0);
            if (t > 0) {
                f16x8 sfrag[3];
#pragma unroll
                for (int nt = 0; nt < 3; ++nt) {
                    int r = nt * 16 + lr;
                    sfrag[nt] = *reinterpret_cast<const f16x8*>(
                        Sc + r * 512 + (cbyte ^ ((r & 7) << 4)));
                }
#pragma unroll
                for (int nt = 0; nt < 3; ++nt)
#pragma unroll
                    for (int et = 0; et < 2; ++et)
                        acc[nt][et] = __builtin_amdgcn_mfma_f32_16x16x32_f16(sfrag[nt], wA[et][ks], acc[nt][et], 0, 0, 0);
            }
        }
        __builtin_amdgcn_s_setprio(0);

        // 4a. stage H_{t+1} (f16) into Hn (vmcnt waits happen here by dep)
        if (has_next) {
#pragma unroll
            for (int j = 0; j < 5; ++j) {
                int idx = j * 512 + tid;
                int r = idx >> 6;
                f16x4 v;
#pragma unroll
                for (int k = 0; k < 4; ++k) v[k] = (_Float16)hreg[j][k];
                *reinterpret_cast<f16x4*>(Hn + r * 512 + (((idx & 63) * 8) ^ ((r & 7) << 4))) = v;
            }
        }

        // 4b. S_t -> Sn (f16, swizzled). Rows 40-47 are pad (never stored).
#pragma unroll
        for (int nt = 0; nt < 3; ++nt) {
#pragma unroll
            for (int et = 0; et < 2; ++et) {
                const int c = wc * 32 + et * 16 + lr;
#pragma unroll
                for (int i = 0; i < 4; ++i) {
                    int r = nt * 16 + kg * 4 + i;
                    *reinterpret_cast<_Float16*>(Sn + r * 512 + ((c * 2) ^ ((r & 7) << 4))) =
                        (_Float16)acc[nt][et][i];
                }
            }
        }

        // 5. single lgkm-only barrier: Sn/Hn complete & visible; global
        //    stores keep draining in the background.
        barrier_lgkm();

        // 6. epilogue: row-contiguous readback of Sn -> coalesced f32 stores.
        //    1280 chunks of 16B (40 real rows x 32 chunks/row); 512 thr x 2.5.
        float* Ot = out + (size_t)t * NROWS * DDIM;
#pragma unroll
        for (int p = 0; p < 3; ++p) {
            int idx = p * 512 + tid;
            if (idx < NCHUNK16) {
                int r   = idx >> 5;                // 0..39 (real rows only)
                int c16 = idx & 31;                // 16B chunk within row
                f16x8 v = *reinterpret_cast<const f16x8*>(
                    Sn + r * 512 + ((c16 * 16) ^ ((r & 7) << 4)));
                int gr = row0 + r;
                f32x4 lo, hi;
#pragma unroll
                for (int k = 0; k < 4; ++k) { lo[k] = (float)v[k]; hi[k] = (float)v[k + 4]; }
                float* dst = Ot + (size_t)gr * DDIM + c16 * 8;
                *reinterpret_cast<f32x4*>(dst)     = lo;
                *reinterpret_cast<f32x4*>(dst + 4) = hi;
            }
        }
        // no second barrier: next step's LDS writes target the opposite
        // buffers; this epilogue's reads complete before this wave's next
        // lgkmcnt(0)+barrier, which precedes any conflicting write (t+2).
    }
}

extern "C" void kernel_launch(void* const* d_in, const int* in_sizes, int n_in,
                              void* d_out, int out_size, void* d_ws, size_t ws_size,
                              hipStream_t stream)
{
    const float* H  = (const float*)d_in[0];
    const float* Aw = (const float*)d_in[1];
    const float* Bw = (const float*)d_in[2];
    const float* Bb = (const float*)d_in[3];
    float* out      = (float*)d_out;

    _Float16* wsA = (_Float16*)d_ws;         // 128 KiB
    _Float16* wsB = wsA + 65536;             // 128 KiB

    cvt_weights_kernel<<<32, 256, 0, stream>>>(Aw, Bw, wsA, wsB);

    int nblocks = NROWS / ROWS_PB;           // 250 (10000/40, exact)
    ssm_fused_kernel<<<nblocks, 512, 0, stream>>>(H, wsA, wsB, Bb, out);
}